// Round 6
// baseline (133.519 us; speedup 1.0000x reference)
//
#include <hip/hip_runtime.h>
#include <math.h>

#define HH 2048
#define WW 2048
#define T 4
#define RING_STRIDE 264            // floats per ring row (256 strip + 8 halo/pad)
#define RING_F (8 * RING_STRIDE)   // floats per wave ring (8-row ring)

// Gaussian sigma=2, 5 taps, normalized
#define GW0 0.15246914402033867f
#define GW1 0.22184129554377693f
#define GW2 0.25137912086578894f

typedef float f2v __attribute__((ext_vector_type(2)));
typedef float f4  __attribute__((ext_vector_type(4)));

struct R8 { float v[8]; };
struct R6 { float v[6]; };
struct Raw { f4 a, b, c; };

__device__ __forceinline__ int reflect_row(int vr) {
    return vr < 0 ? -vr : (vr >= HH ? 2 * HH - 2 - vr : vr);
}

__device__ __forceinline__ Raw load_row3(const float* __restrict__ p, int r, int xb) {
    const float* row = p + (size_t)r * WW;
    Raw o;
    o.a = *(const f4*)(row + max(xb - 4, 0));
    o.b = *(const f4*)(row + xb);
    o.c = *(const f4*)(row + min(xb + 4, WW - 4));
    return o;
}

// horizontal gaussian from raw lab row; output covers x = xb-2 .. xb+5
__device__ __forceinline__ R8 make_h(const Raw& R, bool edgew, bool le, bool re) {
    float w[12] = {R.a.x, R.a.y, R.a.z, R.a.w, R.b.x, R.b.y, R.b.z, R.b.w,
                   R.c.x, R.c.y, R.c.z, R.c.w};
    if (edgew) {
        if (le) { w[0] = R.c.x; w[1] = R.b.w; w[2] = R.b.z; w[3] = R.b.y; }   // reflect left
        if (re) { w[8] = R.b.z; w[9] = R.b.y; w[10] = R.b.x; w[11] = R.a.w; } // reflect right
    }
    R8 h;
    #pragma unroll
    for (int j = 0; j < 8; ++j)
        h.v[j] = GW0 * (w[j] + w[j + 4]) + GW1 * (w[j + 1] + w[j + 3]) + GW2 * w[j + 2];
    return h;
}

// vertical gaussian -> blur row (8-wide), x-clamp fixups for sobel replicate pad
__device__ __forceinline__ R8 vg(const R8& a, const R8& b, const R8& c, const R8& d, const R8& e_,
                                 bool edgew, bool le, bool re) {
    R8 o;
    #pragma unroll
    for (int j = 0; j < 8; ++j)
        o.v[j] = GW0 * (a.v[j] + e_.v[j]) + GW1 * (b.v[j] + d.v[j]) + GW2 * c.v[j];
    if (edgew) {
        if (le) { o.v[0] = o.v[2]; o.v[1] = o.v[2]; }
        if (re) { o.v[6] = o.v[5]; o.v[7] = o.v[5]; }
    }
    return o;
}

// first sobel: 8-wide blur rows -> 6-wide gx,gy (x = xb-1 .. xb+4), x-clamp dup on edges
__device__ __forceinline__ void sobel(const R8& u, const R8& m, const R8& d, R6& ox, R6& oy,
                                      bool edgew, bool le, bool re) {
    #pragma unroll
    for (int j = 0; j < 6; ++j) {
        ox.v[j] = ((u.v[j+2] - u.v[j]) + 2.f*(m.v[j+2] - m.v[j]) + (d.v[j+2] - d.v[j])) * 0.125f;
        oy.v[j] = ((d.v[j] - u.v[j]) + 2.f*(d.v[j+1] - u.v[j+1]) + (d.v[j+2] - u.v[j+2])) * 0.125f;
    }
    if (edgew) {
        if (le) { ox.v[0] = ox.v[1]; oy.v[0] = oy.v[1]; }
        if (re) { ox.v[5] = ox.v[4]; oy.v[5] = oy.v[4]; }
    }
}

// write e-row (slot) into per-wave ring: own 4 cols + edge-lane halo cols
__device__ __forceinline__ void ewrite(float* __restrict__ ring, int slot, int lane,
                                       const f4& pv, const f2v& pl, const f2v& pr,
                                       bool zrow, bool lzero, bool rzero) {
    float* rp = ring + slot * RING_STRIDE;
    if (!zrow) {
        f4 ev;
        ev.x = __expf(pv.x * 10.f); ev.y = __expf(pv.y * 10.f);
        ev.z = __expf(pv.z * 10.f); ev.w = __expf(pv.w * 10.f);
        *(f4*)(rp + 4 + 4 * lane) = ev;
        if (lane == 0) {
            f2v h2; h2.x = lzero ? 0.f : __expf(pl.x * 10.f);
                    h2.y = lzero ? 0.f : __expf(pl.y * 10.f);
            *(f2v*)(rp + 2) = h2;
        }
        if (lane == 63) {
            f2v h2; h2.x = rzero ? 0.f : __expf(pr.x * 10.f);
                    h2.y = rzero ? 0.f : __expf(pr.y * 10.f);
            *(f2v*)(rp + 260) = h2;
        }
    } else {
        f4 z = {0.f, 0.f, 0.f, 0.f};
        *(f4*)(rp + 4 + 4 * lane) = z;
        if (lane == 0)  { f2v z2 = {0.f, 0.f}; *(f2v*)(rp + 2) = z2; }
        if (lane == 63) { f2v z2 = {0.f, 0.f}; *(f2v*)(rp + 260) = z2; }
    }
}

// read 8-wide e window (cols xb-2 .. xb+5) from ring row
__device__ __forceinline__ R8 eread(const float* __restrict__ ring, int slot, int lane) {
    const float* rp = ring + slot * RING_STRIDE + 4 * lane;
    f2v w01 = *(const f2v*)(rp + 2);
    f4  w25 = *(const f4*)(rp + 4);
    f2v w67 = *(const f2v*)(rp + 8);
    R8 o;
    o.v[0] = w01.x; o.v[1] = w01.y; o.v[2] = w25.x; o.v[3] = w25.y;
    o.v[4] = w25.z; o.v[5] = w25.w; o.v[6] = w67.x; o.v[7] = w67.y;
    return o;
}

__global__ __launch_bounds__(256, 4) void steal_main(const float* __restrict__ pred,
                                                     const float* __restrict__ lab,
                                                     float* __restrict__ acc) {
    __shared__ float ring_s[4 * RING_F];        // 33792 B
    const int lane = threadIdx.x & 63;
    const int warp = threadIdx.x >> 6;
    const int wid  = (blockIdx.x << 2) + warp;  // 0..4095
    const int sx = wid & 7;
    const int y0 = (wid >> 3) * T;
    const int xb = sx * 256 + lane * 4;
    const bool edgew = (sx == 0) || (sx == 7);
    const bool le = (sx == 0) && (lane == 0);
    const bool re = (sx == 7) && (lane == 63);
    const bool lzero = (sx == 0), rzero = (sx == 7);
    float* ring = ring_s + warp * RING_F;

    const float T1f = 0.41421356237309503f;   // tan(pi/8)
    const float T3f = 2.41421356237309510f;   // tan(3pi/8)

    // ---------------- prime label pipeline ----------------
    R8 H0, H1, H2, H3, b0, b1;
    R6 gx0, gy0, gx1, gy1;
    {
        Raw r0 = load_row3(lab, reflect_row(y0 - 4), xb);
        Raw r1 = load_row3(lab, reflect_row(y0 - 3), xb);
        Raw r2 = load_row3(lab, reflect_row(y0 - 2), xb);
        Raw r3 = load_row3(lab, reflect_row(y0 - 1), xb);
        R8 A0 = make_h(r0, edgew, le, re);
        R8 A1 = make_h(r1, edgew, le, re);
        R8 A2 = make_h(r2, edgew, le, re);
        R8 A3 = make_h(r3, edgew, le, re);
        Raw r4 = load_row3(lab, y0 + 0, xb);
        Raw r5 = load_row3(lab, y0 + 1, xb);
        Raw r6 = load_row3(lab, y0 + 2, xb);
        Raw r7 = load_row3(lab, y0 + 3, xb);
        H0 = make_h(r4, edgew, le, re);
        H1 = make_h(r5, edgew, le, re);
        H2 = make_h(r6, edgew, le, re);
        H3 = make_h(r7, edgew, le, re);
        R8 bm2 = vg(A0, A1, A2, A3, H0, edgew, le, re);
        R8 bm1 = vg(A1, A2, A3, H0, H1, edgew, le, re);
        b0 = vg(A2, A3, H0, H1, H2, edgew, le, re);
        b1 = vg(A3, H0, H1, H2, H3, edgew, le, re);
        if (y0 > 0) {
            sobel(bm2, bm1, b0, gx0, gy0, edgew, le, re);
            sobel(bm1, b0,  b1, gx1, gy1, edgew, le, re);
        } else {
            sobel(b0, b0, b1, gx1, gy1, edgew, le, re);
            gx0 = gx1; gy0 = gy1;
        }
    }

    // ---------------- prime e-ring: rows y0-2 .. y0+1 ----------------
    #pragma unroll
    for (int j = 0; j < 4; ++j) {
        int ry = y0 - 2 + j;
        bool zrow = (ry < 0);
        const float* prow = pred + (size_t)max(ry, 0) * WW;
        f4 pv = *(const f4*)(prow + xb);
        f2v pl = {0.f, 0.f}, pr = {0.f, 0.f};
        if (lane == 0)  pl = *(const f2v*)(prow + max(xb - 2, 0));
        if (lane == 63) pr = *(const f2v*)(prow + min(xb + 4, WW - 2));
        ewrite(ring, (ry + 4) & 7, lane, pv, pl, pr, zrow, lzero, rzero);
    }

    // ---------------- prefetch for iteration 0 ----------------
    Raw nlab = load_row3(lab, reflect_row(y0 + 4), xb);
    f4 npred; f2v npl = {0.f, 0.f}, npr = {0.f, 0.f};
    {
        const float* prow = pred + (size_t)min(y0 + 2, HH - 1) * WW;
        npred = *(const f4*)(prow + xb);
        if (lane == 0)  npl = *(const f2v*)(prow + max(xb - 2, 0));
        if (lane == 63) npr = *(const f2v*)(prow + min(xb + 4, WW - 2));
    }

    float lsum = 0.f;

    // ---------------- main loop: T output rows ----------------
    #pragma unroll
    for (int i = 0; i < T; ++i) {
        const int y = y0 + i;

        R8 bn;                                           // blur[y+2]
        if (y + 2 < HH) {
            R8 hn = make_h(nlab, edgew, le, re);
            bn = vg(H0, H1, H2, H3, hn, edgew, le, re);
            H0 = H1; H1 = H2; H2 = H3; H3 = hn;
        } else bn = b1;

        // write e row y+2 from prefetched pred
        ewrite(ring, (y + 6) & 7, lane, npred, npl, npr, (y + 2 >= HH), lzero, rzero);

        // prefetch next iteration's raws (independent of current compute)
        if (i < T - 1) {
            nlab = load_row3(lab, reflect_row(y + 5), xb);
            const float* prow = pred + (size_t)min(y + 3, HH - 1) * WW;
            npred = *(const f4*)(prow + xb);
            npl.x = 0.f; npl.y = 0.f; npr.x = 0.f; npr.y = 0.f;
            if (lane == 0)  npl = *(const f2v*)(prow + max(xb - 2, 0));
            if (lane == 63) npr = *(const f2v*)(prow + min(xb + 4, WW - 2));
        }

        R6 gxn, gyn;                                     // gxgy[y+1]
        if (y + 1 < HH) sobel(b0, b1, bn, gxn, gyn, edgew, le, re);
        else { gxn = gx1; gyn = gy1; }

        // read the 5 e windows (rows y-2 .. y+2)
        R8 wA = eread(ring, (y + 2) & 7, lane);
        R8 wB = eread(ring, (y + 3) & 7, lane);
        R8 wC = eread(ring, (y + 4) & 7, lane);
        R8 wD = eread(ring, (y + 5) & 7, lane);
        R8 wE = eread(ring, (y + 6) & 7, lane);

        #pragma unroll
        for (int k = 0; k < 4; ++k) {
            float gxx = ((gx0.v[k+2]-gx0.v[k]) + 2.f*(gx1.v[k+2]-gx1.v[k]) +
                         (gxn.v[k+2]-gxn.v[k])) * 0.125f;
            float gxy = ((gy0.v[k+2]-gy0.v[k]) + 2.f*(gy1.v[k+2]-gy1.v[k]) +
                         (gyn.v[k+2]-gyn.v[k])) * 0.125f;
            float gyy = ((gyn.v[k]-gy0.v[k]) + 2.f*(gyn.v[k+1]-gy0.v[k+1]) +
                         (gyn.v[k+2]-gy0.v[k+2])) * 0.125f;
            float sg = -(gxy + 1e-6f);
            float sgn = (sg > 0.f) ? 1.f : ((sg < 0.f) ? -1.f : 0.f);
            float rt = gyy * sgn * __builtin_amdgcn_rcpf(gxx + 1e-6f);

            float hs  = wC.v[k] + wC.v[k+1] + wC.v[k+2] + wC.v[k+3] + wC.v[k+4];
            float vs  = wA.v[k+2] + wB.v[k+2] + wC.v[k+2] + wD.v[k+2] + wE.v[k+2];
            float dls = wA.v[k]   + wB.v[k+1] + wC.v[k+2] + wD.v[k+3] + wE.v[k+4];
            float dcs = wA.v[k+4] + wB.v[k+3] + wC.v[k+2] + wD.v[k+1] + wE.v[k];

            bool isH = (rt >= -T1f) && (rt < T1f);
            bool isL = (rt >=  T1f) && (rt < T3f);
            bool isC = (rt >= -T3f) && (rt < -T1f);
            bool has = isH || isL || isC || (rt >= T3f) || (rt < -T3f);  // false only for NaN
            float resp = isH ? hs : (isL ? dls : (isC ? dcs : vs));
            float lc = __logf(wC.v[k+2]);                 // == pc*10 (e = exp(pc*10))
            float lv = lc - __logf(resp + 1e-6f);
            lsum += has ? lv : 0.f;
        }

        b0 = b1; b1 = bn;
        gx0 = gx1; gx1 = gxn; gy0 = gy1; gy1 = gyn;
    }

    // ---------------- wave reduction ----------------
    #pragma unroll
    for (int off = 32; off; off >>= 1) lsum += __shfl_down(lsum, off, 64);
    if (lane == 0) acc[wid] = lsum;
}

__global__ __launch_bounds__(256) void steal_finalize(const float* __restrict__ acc,
                                                      float* __restrict__ out, int n) {
    __shared__ double sd[256];
    double a = 0.0;
    int n4 = n >> 2;
    for (int i = threadIdx.x; i < n4; i += 256) {
        f4 v = *(const f4*)(acc + i * 4);
        a += (double)v.x + (double)v.y + (double)v.z + (double)v.w;
    }
    for (int i = (n4 << 2) + threadIdx.x; i < n; i += 256) a += (double)acc[i];
    sd[threadIdx.x] = a;
    __syncthreads();
    for (int s = 128; s > 0; s >>= 1) {
        if (threadIdx.x < s) sd[threadIdx.x] += sd[threadIdx.x + s];
        __syncthreads();
    }
    if (threadIdx.x == 0) out[0] = (float)(-sd[0] / 4194304.0);
}

extern "C" void kernel_launch(void* const* d_in, const int* in_sizes, int n_in,
                              void* d_out, int out_size, void* d_ws, size_t ws_size,
                              hipStream_t stream) {
    const float* pred = (const float*)d_in[0];   // (1,1,2048,2048) f32
    const float* lab  = (const float*)d_in[1];   // (1,2048,2048) f32
    float* out = (float*)d_out;                  // scalar f32
    float* ws  = (float*)d_ws;

    const int nwaves = 8 * (HH / T);             // 4096 wave-jobs
    const int nblocks = nwaves / 4;              // 1024 blocks x 256 threads

    steal_main<<<nblocks, 256, 0, stream>>>(pred, lab, ws);
    steal_finalize<<<1, 256, 0, stream>>>(ws, out, nwaves);
}

// Round 7
// 41.328 us; speedup vs baseline: 3.2307x; 3.2307x over previous
//
#include <hip/hip_runtime.h>
#include <math.h>
#include <stdint.h>

#define HH 2048
#define WW 2048
#define T 4

// Gaussian sigma=2, 5 taps, normalized
#define GW0 0.15246914402033867f
#define GW1 0.22184129554377693f
#define GW2 0.25137912086578894f

typedef float f2v __attribute__((ext_vector_type(2)));
typedef float f4  __attribute__((ext_vector_type(4)));

struct R8 { float v[8]; };
struct R6 { float v[6]; };
struct Raw { f4 a, b, c; };

__device__ __forceinline__ int reflect_row(int vr) {
    return vr < 0 ? -vr : (vr >= HH ? 2 * HH - 2 - vr : vr);
}

__device__ __forceinline__ Raw load_row3(const float* __restrict__ p, int r, int xb) {
    const float* row = p + (size_t)r * WW;
    Raw o;
    o.a = *(const f4*)(row + max(xb - 4, 0));
    o.b = *(const f4*)(row + xb);
    o.c = *(const f4*)(row + min(xb + 4, WW - 4));
    return o;
}

// horizontal gaussian from raw lab row; output covers x = xb-2 .. xb+5
__device__ __forceinline__ R8 make_h(const Raw& R, bool edgew, bool le, bool re) {
    float w[12] = {R.a.x, R.a.y, R.a.z, R.a.w, R.b.x, R.b.y, R.b.z, R.b.w,
                   R.c.x, R.c.y, R.c.z, R.c.w};
    if (edgew) {
        if (le) { w[0] = R.c.x; w[1] = R.b.w; w[2] = R.b.z; w[3] = R.b.y; }   // reflect left
        if (re) { w[8] = R.b.z; w[9] = R.b.y; w[10] = R.b.x; w[11] = R.a.w; } // reflect right
    }
    R8 h;
    #pragma unroll
    for (int j = 0; j < 8; ++j)
        h.v[j] = GW0 * (w[j] + w[j + 4]) + GW1 * (w[j + 1] + w[j + 3]) + GW2 * w[j + 2];
    return h;
}

// vertical gaussian -> blur row (8-wide), x-clamp fixups for sobel replicate pad
__device__ __forceinline__ R8 vg(const R8& a, const R8& b, const R8& c, const R8& d, const R8& e_,
                                 bool edgew, bool le, bool re) {
    R8 o;
    #pragma unroll
    for (int j = 0; j < 8; ++j)
        o.v[j] = GW0 * (a.v[j] + e_.v[j]) + GW1 * (b.v[j] + d.v[j]) + GW2 * c.v[j];
    if (edgew) {
        if (le) { o.v[0] = o.v[2]; o.v[1] = o.v[2]; }
        if (re) { o.v[6] = o.v[5]; o.v[7] = o.v[5]; }
    }
    return o;
}

// first sobel: 8-wide blur rows -> 6-wide gx,gy (x = xb-1 .. xb+4), x-clamp dup on edges
__device__ __forceinline__ void sobel(const R8& u, const R8& m, const R8& d, R6& ox, R6& oy,
                                      bool edgew, bool le, bool re) {
    #pragma unroll
    for (int j = 0; j < 6; ++j) {
        ox.v[j] = ((u.v[j+2] - u.v[j]) + 2.f*(m.v[j+2] - m.v[j]) + (d.v[j+2] - d.v[j])) * 0.125f;
        oy.v[j] = ((d.v[j] - u.v[j]) + 2.f*(d.v[j+1] - u.v[j+1]) + (d.v[j+2] - u.v[j+2])) * 0.125f;
    }
    if (edgew) {
        if (le) { ox.v[0] = ox.v[1]; oy.v[0] = oy.v[1]; }
        if (re) { ox.v[5] = ox.v[4]; oy.v[5] = oy.v[4]; }
    }
}

// e = exp(pred*10) row, 8-wide covering x = xb-2 .. xb+5, zero outside image.
__device__ __forceinline__ R8 erow(const float* __restrict__ pred, int ry, int xb,
                                   bool edgew, bool le, bool re) {
    R8 o;
    if (ry < 0 || ry >= HH) {           // wave-uniform
        #pragma unroll
        for (int j = 0; j < 8; ++j) o.v[j] = 0.f;
        return o;
    }
    const float* row = pred + (size_t)ry * WW;
    f4 A = *(const f4*)(row + max(xb - 4, 0));
    f4 B = *(const f4*)(row + xb);
    f4 C = *(const f4*)(row + min(xb + 4, WW - 4));
    float w[8] = {A.z, A.w, B.x, B.y, B.z, B.w, C.x, C.y};
    #pragma unroll
    for (int j = 0; j < 8; ++j) o.v[j] = __expf(w[j] * 10.f);
    if (edgew) {
        if (le) { o.v[0] = 0.f; o.v[1] = 0.f; }
        if (re) { o.v[6] = 0.f; o.v[7] = 0.f; }
    }
    return o;
}

// =================== Kernel A: labels -> packed section codes ===================
__global__ __launch_bounds__(256) void steal_sections(const float* __restrict__ lab,
                                                      uint32_t* __restrict__ codes) {
    const int lane = threadIdx.x & 63;
    const int wid  = (blockIdx.x << 2) + (threadIdx.x >> 6);   // 0..4095
    const int sx = wid & 7;
    const int y0 = (wid >> 3) * T;
    const int xb = sx * 256 + lane * 4;
    const bool edgew = (sx == 0) || (sx == 7);
    const bool le = (sx == 0) && (lane == 0);
    const bool re = (sx == 7) && (lane == 63);

    const float T1f = 0.41421356237309503f;   // tan(pi/8)
    const float T3f = 2.41421356237309510f;   // tan(3pi/8)

    // ---------------- prime label pipeline ----------------
    R8 H0, H1, H2, H3, b0, b1;
    R6 gx0, gy0, gx1, gy1;
    {
        Raw r0 = load_row3(lab, reflect_row(y0 - 4), xb);
        Raw r1 = load_row3(lab, reflect_row(y0 - 3), xb);
        Raw r2 = load_row3(lab, reflect_row(y0 - 2), xb);
        Raw r3 = load_row3(lab, reflect_row(y0 - 1), xb);
        R8 A0 = make_h(r0, edgew, le, re);
        R8 A1 = make_h(r1, edgew, le, re);
        R8 A2 = make_h(r2, edgew, le, re);
        R8 A3 = make_h(r3, edgew, le, re);
        Raw r4 = load_row3(lab, y0 + 0, xb);
        Raw r5 = load_row3(lab, y0 + 1, xb);
        Raw r6 = load_row3(lab, y0 + 2, xb);
        Raw r7 = load_row3(lab, y0 + 3, xb);
        H0 = make_h(r4, edgew, le, re);
        H1 = make_h(r5, edgew, le, re);
        H2 = make_h(r6, edgew, le, re);
        H3 = make_h(r7, edgew, le, re);
        R8 bm2 = vg(A0, A1, A2, A3, H0, edgew, le, re);
        R8 bm1 = vg(A1, A2, A3, H0, H1, edgew, le, re);
        b0 = vg(A2, A3, H0, H1, H2, edgew, le, re);
        b1 = vg(A3, H0, H1, H2, H3, edgew, le, re);
        if (y0 > 0) {
            sobel(bm2, bm1, b0, gx0, gy0, edgew, le, re);
            sobel(bm1, b0,  b1, gx1, gy1, edgew, le, re);
        } else {
            sobel(b0, b0, b1, gx1, gy1, edgew, le, re);
            gx0 = gx1; gy0 = gy1;
        }
    }

    #pragma unroll
    for (int i = 0; i < T; ++i) {
        const int y = y0 + i;

        R8 bn;                                           // blur[y+2]
        if (y + 2 < HH) {
            R8 hn = make_h(load_row3(lab, reflect_row(y + 4), xb), edgew, le, re);
            bn = vg(H0, H1, H2, H3, hn, edgew, le, re);
            H0 = H1; H1 = H2; H2 = H3; H3 = hn;
        } else bn = b1;

        R6 gxn, gyn;                                     // gxgy[y+1]
        if (y + 1 < HH) sobel(b0, b1, bn, gxn, gyn, edgew, le, re);
        else { gxn = gx1; gyn = gy1; }

        uint32_t cw = 0;
        #pragma unroll
        for (int k = 0; k < 4; ++k) {
            float gxx = ((gx0.v[k+2]-gx0.v[k]) + 2.f*(gx1.v[k+2]-gx1.v[k]) +
                         (gxn.v[k+2]-gxn.v[k])) * 0.125f;
            float gxy = ((gy0.v[k+2]-gy0.v[k]) + 2.f*(gy1.v[k+2]-gy1.v[k]) +
                         (gyn.v[k+2]-gyn.v[k])) * 0.125f;
            float gyy = ((gyn.v[k]-gy0.v[k]) + 2.f*(gyn.v[k+1]-gy0.v[k+1]) +
                         (gyn.v[k+2]-gy0.v[k+2])) * 0.125f;
            float sg = -(gxy + 1e-6f);
            float sgn = (sg > 0.f) ? 1.f : ((sg < 0.f) ? -1.f : 0.f);
            float rt = gyy * sgn * __builtin_amdgcn_rcpf(gxx + 1e-6f);

            bool isH = (rt >= -T1f) && (rt < T1f);
            bool isL = (rt >=  T1f) && (rt < T3f);
            bool isC = (rt >= -T3f) && (rt < -T1f);
            bool isV = (rt >= T3f) || (rt < -T3f);
            uint32_t c = isH ? 0u : (isL ? 1u : (isC ? 2u : (isV ? 3u : 4u)));
            cw |= c << (8 * k);
        }
        codes[((size_t)y * WW + xb) >> 2] = cw;

        b0 = b1; b1 = bn;
        gx0 = gx1; gx1 = gxn; gy0 = gy1; gy1 = gyn;
    }
}

// =================== Kernel B: pred + codes -> loss partials ===================
__global__ __launch_bounds__(256) void steal_loss(const float* __restrict__ pred,
                                                  const uint32_t* __restrict__ codes,
                                                  float* __restrict__ acc) {
    const int lane = threadIdx.x & 63;
    const int wid  = (blockIdx.x << 2) + (threadIdx.x >> 6);   // 0..4095
    const int sx = wid & 7;
    const int y0 = (wid >> 3) * T;
    const int xb = sx * 256 + lane * 4;
    const bool edgew = (sx == 0) || (sx == 7);
    const bool le = (sx == 0) && (lane == 0);
    const bool re = (sx == 7) && (lane == 63);

    // prime e window: rows y0-2 .. y0+1
    R8 e0 = erow(pred, y0 - 2, xb, edgew, le, re);
    R8 e1 = erow(pred, y0 - 1, xb, edgew, le, re);
    R8 e2 = erow(pred, y0 + 0, xb, edgew, le, re);
    R8 e3 = erow(pred, y0 + 1, xb, edgew, le, re);

    float lsum = 0.f;

    #pragma unroll
    for (int i = 0; i < T; ++i) {
        const int y = y0 + i;
        R8 en = erow(pred, y + 2, xb, edgew, le, re);

        f4 pc4 = *(const f4*)(pred + (size_t)y * WW + xb);
        float pcv[4] = {pc4.x, pc4.y, pc4.z, pc4.w};
        uint32_t cw = codes[((size_t)y * WW + xb) >> 2];

        #pragma unroll
        for (int k = 0; k < 4; ++k) {
            float hs  = e2.v[k] + e2.v[k+1] + e2.v[k+2] + e2.v[k+3] + e2.v[k+4];
            float vs  = e0.v[k+2] + e1.v[k+2] + e2.v[k+2] + e3.v[k+2] + en.v[k+2];
            float dls = e0.v[k]   + e1.v[k+1] + e2.v[k+2] + e3.v[k+3] + en.v[k+4];
            float dcs = e0.v[k+4] + e1.v[k+3] + e2.v[k+2] + e3.v[k+1] + en.v[k];

            uint32_t c = (cw >> (8 * k)) & 0xffu;
            float resp = (c == 0u) ? hs : ((c == 1u) ? dls : ((c == 2u) ? dcs : vs));
            float lv = pcv[k] * 10.f - __logf(resp + 1e-6f);
            lsum += (c < 4u) ? lv : 0.f;
        }

        e0 = e1; e1 = e2; e2 = e3; e3 = en;
    }

    #pragma unroll
    for (int off = 32; off; off >>= 1) lsum += __shfl_down(lsum, off, 64);
    if (lane == 0) acc[wid] = lsum;
}

__global__ __launch_bounds__(256) void steal_finalize(const float* __restrict__ acc,
                                                      float* __restrict__ out, int n) {
    __shared__ double sd[256];
    double a = 0.0;
    int n4 = n >> 2;
    for (int i = threadIdx.x; i < n4; i += 256) {
        f4 v = *(const f4*)(acc + i * 4);
        a += (double)v.x + (double)v.y + (double)v.z + (double)v.w;
    }
    for (int i = (n4 << 2) + threadIdx.x; i < n; i += 256) a += (double)acc[i];
    sd[threadIdx.x] = a;
    __syncthreads();
    for (int s = 128; s > 0; s >>= 1) {
        if (threadIdx.x < s) sd[threadIdx.x] += sd[threadIdx.x + s];
        __syncthreads();
    }
    if (threadIdx.x == 0) out[0] = (float)(-sd[0] / 4194304.0);
}

extern "C" void kernel_launch(void* const* d_in, const int* in_sizes, int n_in,
                              void* d_out, int out_size, void* d_ws, size_t ws_size,
                              hipStream_t stream) {
    const float* pred = (const float*)d_in[0];   // (1,1,2048,2048) f32
    const float* lab  = (const float*)d_in[1];   // (1,2048,2048) f32
    float* out = (float*)d_out;                  // scalar f32

    uint32_t* codes = (uint32_t*)d_ws;                               // 4 MB
    float* accb = (float*)((uint8_t*)d_ws + (size_t)HH * WW);        // 16 KB after codes

    const int nwaves = 8 * (HH / T);             // 4096 wave-jobs
    const int nblocks = nwaves / 4;              // 1024 blocks x 256 threads

    steal_sections<<<nblocks, 256, 0, stream>>>(lab, codes);
    steal_loss<<<nblocks, 256, 0, stream>>>(pred, codes, accb);
    steal_finalize<<<1, 256, 0, stream>>>(accb, out, nwaves);
}